// Round 8
// baseline (219.537 us; speedup 1.0000x reference)
//
#include <hip/hip_runtime.h>

typedef __attribute__((ext_vector_type(8))) short bf16x8;
typedef __attribute__((ext_vector_type(4))) float f32x4;

__device__ __forceinline__ float bf2f(unsigned short u) {
  return __uint_as_float(((unsigned int)u) << 16);
}
__device__ __forceinline__ unsigned short f2bf(float f) {
  unsigned int u = __float_as_uint(f);
  u += 0x7fffu + ((u >> 16) & 1u);
  return (unsigned short)(u >> 16);
}

// ---------------- workspace layout (bytes) ----------------
constexpr size_t OFF_XPAD = 0;
constexpr size_t SZ_XPAD  = (size_t)8 * 66 * 66 * 128 * 2;        // 8,921,088
constexpr size_t OFF_WB   = OFF_XPAD + SZ_XPAD;
constexpr size_t SZ_WB    = (size_t)9 * 16 * 256 * 8 * 2;         // 589,824
constexpr size_t OFF_WS2  = OFF_WB + SZ_WB;
constexpr size_t SZ_WS2   = (size_t)16 * 256 * 8 * 2;             // 65,536
constexpr size_t OFF_WO   = OFF_WS2 + SZ_WS2;
constexpr size_t SZ_WO    = (size_t)9 * 16 * 32 * 8 * 2;          // 73,728
// y_main bf16, FRAGMENT-LINEAR: [512 blocks][512 threads][32 elems]
constexpr size_t OFF_YM   = OFF_WO + SZ_WO;
constexpr size_t SZ_YM    = (size_t)512 * 512 * 32 * 2;           // 16,777,216
constexpr size_t OFF_SR   = OFF_YM + SZ_YM;                        // statsRaw [8][256][2] f32
constexpr size_t SZ_SR    = (size_t)8 * 256 * 2 * 4;              // 16,384

// XCD swizzle: xcd = blockIdx.x % 8. b = blk&7 -> batch b on XCD b; per-XCD L2
// working set = 1 batch xpad (1.1MB) + weights. Verified R2: FETCH 26.4->7.3MB.
// BN stats via per-batch atomics into statsRaw (verified R6).
// R7: k_main and k_final share identical 512x512 geometry -> ymain stored/loaded
// as raw MFMA fragments (thread-linear, 64B/thread) -> no epilogue LDS transpose
// in k_main, no ymain LDS pass in k_final.

// ---------------- prep: x transpose (0..511) + weight pack (512..689) + stats zero (690) ----------------
__global__ __launch_bounds__(256) void k_prep(const float* __restrict__ x,
                                              unsigned short* __restrict__ xp,
                                              const float* __restrict__ wdef,
                                              const float* __restrict__ wsc,
                                              const float* __restrict__ woff,
                                              unsigned short* __restrict__ wB,
                                              unsigned short* __restrict__ wS,
                                              unsigned short* __restrict__ wO,
                                              float* __restrict__ statsRaw) {
  int t = threadIdx.x;
  if (blockIdx.x == 690) {            // zero BN accumulators (graph-replay safe)
    for (int i = t; i < 4096; i += 256) statsRaw[i] = 0.f;
    return;
  }
  if (blockIdx.x >= 512) {            // ---- weight packing: 8 contiguous elems/thread ----
    int base = ((blockIdx.x - 512) * 256 + t) * 8;
    unsigned short w8[8];
    if (base < 294912) {
      int n = (base >> 3) & 255, kb = (base >> 11) & 15, tap = base >> 15;
#pragma unroll
      for (int j = 0; j < 8; ++j)
        w8[j] = f2bf(wdef[((size_t)n * 128 + kb * 8 + j) * 9 + tap]);
      *(bf16x8*)(wB + base) = *(const bf16x8*)w8;
    } else if (base < 327680) {
      int i0 = base - 294912;
      int n = (i0 >> 3) & 255, kb = i0 >> 11;
#pragma unroll
      for (int j = 0; j < 8; ++j)
        w8[j] = f2bf(wsc[(size_t)n * 128 + kb * 8 + j]);
      *(bf16x8*)(wS + i0) = *(const bf16x8*)w8;
    } else {
      int i0 = base - 327680;
      int n = (i0 >> 3) & 31, kb = (i0 >> 8) & 15, tap = i0 >> 12;
#pragma unroll
      for (int j = 0; j < 8; ++j)
        w8[j] = f2bf(n < 18 ? woff[((size_t)n * 128 + kb * 8 + j) * 9 + tap] : 0.f);
      *(bf16x8*)(wO + i0) = *(const bf16x8*)w8;
    }
    return;
  }
  // ---- x: NCHW fp32 -> NHWC bf16 zero-padded (+ halo zeroing) ----
  int blk = blockIdx.x;               // 512; b = blk&7 (XCD-local), h = blk>>3
  int b = blk & 7, h = blk >> 3;
  __shared__ unsigned short xt[128 * 68];   // [c][w], stride 68
  {
    unsigned short* base = xp + (size_t)b * 66 * 66 * 128;
    ushort4 z4 = {0, 0, 0, 0};
    if (t < 64) {                     // side columns of padded row h+1
      int col = (t >> 5) ? 65 : 0;
      int i = t & 31;
      *(ushort4*)(base + ((size_t)(h + 1) * 66 + col) * 128 + i * 4) = z4;
    }
    if (h == 0) {                     // top and bottom padded rows
      for (int i = t; i < 2112; i += 256) {
        *(ushort4*)(base + (size_t)i * 4) = z4;
        *(ushort4*)(base + (size_t)65 * 66 * 128 + (size_t)i * 4) = z4;
      }
    }
  }
  {
    // lane-coalesced load: consecutive lanes -> consecutive float4
#pragma unroll
    for (int i4 = 0; i4 < 8; ++i4) {
      int idx = t + i4 * 256;         // 0..2047 over 128 rows x 16 float4
      int row = idx >> 4, col = (idx & 15) * 4;
      float4 f = *(const float4*)&x[(((size_t)b * 128 + row) * 64 + h) * 64 + col];
      ushort4 u4;
      u4.x = f2bf(f.x); u4.y = f2bf(f.y); u4.z = f2bf(f.z); u4.w = f2bf(f.w);
      *(ushort4*)&xt[row * 68 + col] = u4;
    }
  }
  __syncthreads();
  {
    // column gather: lane = w (2-way bank alias only), cg = channel group
    int w = t & 63, cg = t >> 6;
    unsigned short tmp[32];
#pragma unroll
    for (int i = 0; i < 32; ++i) tmp[i] = xt[(cg * 32 + i) * 68 + w];
    unsigned short* dst = xp + ((size_t)(b * 66 + h + 1) * 66 + (w + 1)) * 128 + cg * 32;
#pragma unroll
    for (int i8 = 0; i8 < 4; ++i8)
      *(bf16x8*)(dst + i8 * 8) = *(const bf16x8*)&tmp[i8 * 8];
  }
}

// ---------------- main: offset conv + deform-sample + 3x3 conv GEMM + BN atomics ----------------
// 512 blocks x 512 thr (8 waves); Breg preload keeps MFMA off the vmcnt FIFO chain.
// Epilogue: fragment-linear ymain dump (no LDS, no barriers).
__global__ __launch_bounds__(512, 4) void k_main(const unsigned short* __restrict__ xp,
                                                 const unsigned short* __restrict__ wB,
                                                 const unsigned short* __restrict__ wO,
                                                 const float* __restrict__ boff,
                                                 const float* __restrict__ bdef,
                                                 unsigned short* __restrict__ ymain,
                                                 float* __restrict__ statsRaw) {
  int blk = blockIdx.x;               // 512; b = blk&7 (XCD-local), h = blk>>3
  int b = blk & 7, h = blk >> 3;
  int t = threadIdx.x;
  int lane = t & 63, wid = t >> 6;    // 8 waves
  int m = lane & 15, quad = lane >> 4;
  __shared__ __align__(16) unsigned short At[2][64 * 136];  // 2 x 17408 B
  __shared__ float offsL[9][64][2];                          // 4608 B

  // ---- phase 0: inline offset conv (waves 0-3 compute this row's 18 offsets -> LDS) ----
  if (wid < 4) {
    f32x4 a0 = {0.f, 0.f, 0.f, 0.f}, a1 = {0.f, 0.f, 0.f, 0.f};
    int px = wid * 16 + m;
    const unsigned short* xbase = xp + ((size_t)(b * 66 + h) * 66 + px) * 128 + quad * 8;
    for (int tap = 0; tap < 9; ++tap) {
      const unsigned short* arow = xbase + ((tap / 3) * 66 + (tap % 3)) * 128;
#pragma unroll
      for (int kk = 0; kk < 4; ++kk) {
        bf16x8 a = *(const bf16x8*)(arow + kk * 32);
        const unsigned short* bb = wO + (size_t)(tap * 16 + kk * 4 + quad) * 256;
        bf16x8 b0 = *(const bf16x8*)(bb + m * 8);
        bf16x8 b1 = *(const bf16x8*)(bb + (16 + m) * 8);
        a0 = __builtin_amdgcn_mfma_f32_16x16x32_bf16(a, b0, a0, 0, 0, 0);
        a1 = __builtin_amdgcn_mfma_f32_16x16x32_bf16(a, b1, a1, 0, 0, 0);
      }
    }
#pragma unroll
    for (int r = 0; r < 4; ++r) {
      int pxs = wid * 16 + quad * 4 + r;
      offsL[m >> 1][pxs][m & 1] = a0[r] + boff[m];   // n=m in [0,16): tap=n>>1, comp=n&1
      if (m < 2) offsL[8][pxs][m] = a1[r] + boff[16 + m];
    }
  }

  f32x4 acc[4][2];
#pragma unroll
  for (int i = 0; i < 4; ++i)
#pragma unroll
    for (int j = 0; j < 2; ++j) acc[i][j] = (f32x4){0.f, 0.f, 0.f, 0.f};

  // sampling role: thread = px_s*8 + sub; 8 consecutive lanes cover one 128B chunk
  int px_s = t >> 3, sub = t & 7;
  const unsigned short* xb_base = xp + (size_t)b * 66 * 66 * 128;
  int nb = wid * 32;                  // mfma role: 32-ch N slice per wave, M=64 shared

  bf16x8 Breg[4][2];                  // this tap's wB fragments, preloaded
  auto loadB = [&](int tap) {
#pragma unroll
    for (int kk = 0; kk < 4; ++kk)
#pragma unroll
      for (int ns = 0; ns < 2; ++ns)
        Breg[kk][ns] = *(const bf16x8*)(wB + ((size_t)(tap * 16 + kk * 4 + quad) * 256 + nb + ns * 16 + m) * 8);
  };

  auto sample_prep = [&](int tap, float* wgt, const unsigned short** p) {
    float2 ov = *(const float2*)&offsL[tap][px_s][0];
    int ky = tap / 3 - 1, kx = tap % 3 - 1;
    float py = (float)(h + ky) + ov.x;
    float pxf = (float)(px_s + kx) + ov.y;
    float y0f = floorf(py), x0f = floorf(pxf);
    float fy = py - y0f, fx = pxf - x0f;
    int iy0 = (int)y0f, ix0 = (int)x0f;
#pragma unroll
    for (int j = 0; j < 4; ++j) {
      int iy = iy0 + (j >> 1), ix = ix0 + (j & 1);
      float wy = (j >> 1) ? fy : 1.f - fy;
      float wx = (j & 1) ? fx : 1.f - fx;
      bool valid = (iy >= 0) && (iy < 64) && (ix >= 0) && (ix < 64);
      int iyc = min(max(iy, 0), 63), ixc = min(max(ix, 0), 63);
      wgt[j] = valid ? wy * wx : 0.f;
      p[j] = xb_base + ((size_t)(iyc + 1) * 66 + (ixc + 1)) * 128 + sub * 8;
    }
  };
  auto load_g1 = [&](const unsigned short** p, int g, bf16x8* v) {
#pragma unroll
    for (int j = 0; j < 4; ++j)
      v[j] = *(const bf16x8*)(p[j] + g * 64);
  };
  auto store_g1 = [&](unsigned short* dst, int g, const float* wgt, bf16x8* v) {
    bf16x8 o;
#pragma unroll
    for (int j = 0; j < 8; ++j) {
      float s = fmaf(wgt[0], bf2f((unsigned short)v[0][j]),
                fmaf(wgt[1], bf2f((unsigned short)v[1][j]),
                fmaf(wgt[2], bf2f((unsigned short)v[2][j]),
                     wgt[3] * bf2f((unsigned short)v[3][j]))));
      o[j] = (short)f2bf(s);
    }
    *(bf16x8*)(dst + g * 64) = o;
  };
  auto mfma_half = [&](const unsigned short* buf, int kk0) {
#pragma unroll
    for (int kk = kk0; kk < kk0 + 2; ++kk) {
      bf16x8 af[4];
#pragma unroll
      for (int ms = 0; ms < 4; ++ms)
        af[ms] = *(const bf16x8*)(buf + (ms * 16 + m) * 136 + kk * 32 + quad * 8);
#pragma unroll
      for (int ns = 0; ns < 2; ++ns)
#pragma unroll
        for (int ms = 0; ms < 4; ++ms)
          acc[ms][ns] = __builtin_amdgcn_mfma_f32_16x16x32_bf16(af[ms], Breg[kk][ns], acc[ms][ns], 0, 0, 0);
    }
  };

  // prologue: B-frags for tap 0, then sample tap 0 into buf 0
  loadB(0);
  __syncthreads();                    // offsL ready
  {
    float wgt[4]; const unsigned short* p[4]; bf16x8 v0[4], v1[4];
    sample_prep(0, wgt, p);
    unsigned short* dst = &At[0][px_s * 136 + sub * 8];
    load_g1(p, 0, v0); load_g1(p, 1, v1);
    store_g1(dst, 0, wgt, v0); store_g1(dst, 1, wgt, v1);
  }
#pragma unroll
  for (int tap = 0; tap < 9; ++tap) {
    __syncthreads();
    const unsigned short* cur = At[tap & 1];
    unsigned short* dst = &At[(tap + 1) & 1][px_s * 136 + sub * 8];
    if (tap < 8) {
      float wgt[4]; const unsigned short* p[4]; bf16x8 v0[4], v1[4];
      sample_prep(tap + 1, wgt, p);
      load_g1(p, 0, v0);
      load_g1(p, 1, v1);
      mfma_half(cur, 0);              // regs + ds_read only: no vmcnt dependence
      store_g1(dst, 0, wgt, v0);
      mfma_half(cur, 2);
      loadB(tap + 1);                 // prefetch next tap's B
      store_g1(dst, 1, wgt, v1);
    } else {
      mfma_half(cur, 0);
      mfma_half(cur, 2);
    }
  }

  // ---- epilogue: bias + BN atomics + fragment-linear ymain dump (no LDS) ----
#pragma unroll
  for (int ns = 0; ns < 2; ++ns) {
    int n = nb + ns * 16 + m;
    float bias = bdef[n];
    float s = 0.f, q = 0.f;
#pragma unroll
    for (int ms = 0; ms < 4; ++ms)
#pragma unroll
      for (int r = 0; r < 4; ++r) {
        float v = acc[ms][ns][r] + bias;
        acc[ms][ns][r] = v;
        s += v;
        q += v * v;
      }
    s += __shfl_xor(s, 16); s += __shfl_xor(s, 32);
    q += __shfl_xor(q, 16); q += __shfl_xor(q, 32);
    if (quad == 0) {                  // 64 blocks share each address (batch-local)
      atomicAdd(&statsRaw[((size_t)b * 256 + n) * 2 + 0], s);
      atomicAdd(&statsRaw[((size_t)b * 256 + n) * 2 + 1], q);
    }
  }
  {
    unsigned short yfrag[32];
#pragma unroll
    for (int ns = 0; ns < 2; ++ns)
#pragma unroll
      for (int ms = 0; ms < 4; ++ms)
#pragma unroll
        for (int r = 0; r < 4; ++r)
          yfrag[ns * 16 + ms * 4 + r] = f2bf(acc[ms][ns][r]);
    unsigned short* dst = ymain + ((size_t)blk * 512 + t) * 32;
#pragma unroll
    for (int k = 0; k < 4; ++k)
      __builtin_nontemporal_store(*(const bf16x8*)&yfrag[k * 8], (bf16x8*)(dst + k * 8));
  }
}

// ---------------- final: stats finalize + 1x1 shortcut MFMA + BN apply + ReLU + NCHW store ----------------
// SAME 512x512 geometry as k_main: ymain read back as raw fragments (coalesced 64B/thread),
// combined in registers; LDS used once for the NCHW transpose-store (per 128-ch half).
__global__ __launch_bounds__(512, 4) void k_final(const unsigned short* __restrict__ xp,
                                                  const unsigned short* __restrict__ wS,
                                                  const unsigned short* __restrict__ ymain,
                                                  const float* __restrict__ statsRaw,
                                                  const float* __restrict__ gamma,
                                                  const float* __restrict__ beta,
                                                  const float* __restrict__ bsc,
                                                  float* __restrict__ out) {
  int blk = blockIdx.x;               // 512; b = blk&7 (XCD-local), h = blk>>3
  int b = blk & 7, h = blk >> 3;
  int t = threadIdx.x;
  int lane = t & 63, wid = t >> 6;
  int m = lane & 15, quad = lane >> 4;
  __shared__ __align__(16) float tr[128 * 68]; // 34,816 B (one 128-ch half x 64 px)
  __shared__ float sAB[512];                   // [0:256) scale, [256:512) shift
  // stats finalize (8 adds/channel from 16KB L2-resident buffer)
  if (t < 256) {
    float s = 0.f, q = 0.f;
#pragma unroll
    for (int i = 0; i < 8; ++i) {
      float2 pq = *(const float2*)&statsRaw[((size_t)i * 256 + t) * 2];
      s += pq.x;
      q += pq.y;
    }
    float mean = s * (1.f / 32768.f);
    float var = q * (1.f / 32768.f) - mean * mean;
    float inv = rsqrtf(var + 1e-5f);
    float A = gamma[t] * inv;
    sAB[t] = A;
    sAB[256 + t] = beta[t] - mean * A;
  }
  // 1x1 shortcut MFMA, k_main geometry: M=64 px, per-wave N=32
  f32x4 accS[4][2];
#pragma unroll
  for (int i = 0; i < 4; ++i)
#pragma unroll
    for (int j = 0; j < 2; ++j) accS[i][j] = (f32x4){0.f, 0.f, 0.f, 0.f};
  const unsigned short* xrow = xp + ((size_t)(b * 66 + h + 1) * 66 + 1) * 128;
  int nb = wid * 32;
#pragma unroll
  for (int kk = 0; kk < 4; ++kk) {
    bf16x8 af[4];
#pragma unroll
    for (int ms = 0; ms < 4; ++ms)
      af[ms] = *(const bf16x8*)(xrow + (ms * 16 + m) * 128 + kk * 32 + quad * 8);
#pragma unroll
    for (int ns = 0; ns < 2; ++ns) {
      bf16x8 bfr = *(const bf16x8*)(wS + ((size_t)(kk * 4 + quad) * 256 + nb + ns * 16 + m) * 8);
#pragma unroll
      for (int ms = 0; ms < 4; ++ms)
        accS[ms][ns] = __builtin_amdgcn_mfma_f32_16x16x32_bf16(af[ms], bfr, accS[ms][ns], 0, 0, 0);
    }
  }
  // y fragments back, thread-linear (perfectly coalesced)
  bf16x8 yf[4];
  {
    const unsigned short* ysrc = ymain + ((size_t)blk * 512 + t) * 32;
#pragma unroll
    for (int k = 0; k < 4; ++k)
      yf[k] = __builtin_nontemporal_load((const bf16x8*)(ysrc + k * 8));
  }
  __syncthreads();                    // sAB ready
  int pass_own = wid >> 2;            // waves 0-3 own n<128, waves 4-7 own n>=128
  for (int pass = 0; pass < 2; ++pass) {
    if (pass_own == pass) {
#pragma unroll
      for (int ns = 0; ns < 2; ++ns) {
        int n = nb + ns * 16 + m;
        float A = sAB[n], Bc = sAB[256 + n], bs = bsc[n];
        int nl = n - pass * 128;
#pragma unroll
        for (int ms = 0; ms < 4; ++ms)
#pragma unroll
          for (int r = 0; r < 4; ++r) {
            int e = ns * 16 + ms * 4 + r;
            float y = bf2f((unsigned short)yf[e >> 3][e & 7]);
            float v = fmaf(y, A, Bc) + accS[ms][ns][r] + bs;
            tr[nl * 68 + ms * 16 + quad * 4 + r] = fmaxf(v, 0.f);
          }
      }
    }
    __syncthreads();
    {
      int nl = t >> 2, q4 = t & 3;    // 128 ch-rows x 4 px-quarters
      float* orow = out + ((size_t)(b * 256 + pass * 128 + nl) * 64 + h) * 64 + q4 * 16;
      const float* lrow = &tr[nl * 68 + q4 * 16];
#pragma unroll
      for (int i4 = 0; i4 < 4; ++i4) {
        f32x4 v = *(const f32x4*)(lrow + i4 * 4);
        __builtin_nontemporal_store(v, (f32x4*)(orow + i4 * 4));
      }
    }
    __syncthreads();
  }
}

extern "C" void kernel_launch(void* const* d_in, const int* in_sizes, int n_in,
                              void* d_out, int out_size, void* d_ws, size_t ws_size,
                              hipStream_t stream) {
  const float* x     = (const float*)d_in[0];
  const float* w_off = (const float*)d_in[1];
  const float* b_off = (const float*)d_in[2];
  const float* w_def = (const float*)d_in[3];
  const float* b_def = (const float*)d_in[4];
  const float* gamma = (const float*)d_in[5];
  const float* beta  = (const float*)d_in[6];
  const float* w_sc  = (const float*)d_in[7];
  const float* b_sc  = (const float*)d_in[8];
  float* out = (float*)d_out;

  char* ws = (char*)d_ws;
  unsigned short* xpad  = (unsigned short*)(ws + OFF_XPAD);
  unsigned short* wB    = (unsigned short*)(ws + OFF_WB);
  unsigned short* wS    = (unsigned short*)(ws + OFF_WS2);
  unsigned short* wO    = (unsigned short*)(ws + OFF_WO);
  unsigned short* ymain = (unsigned short*)(ws + OFF_YM);
  float* statsRaw       = (float*)(ws + OFF_SR);

  k_prep<<<691, 256, 0, stream>>>(x, xpad, w_def, w_sc, w_off, wB, wS, wO, statsRaw);
  k_main<<<512, 512, 0, stream>>>(xpad, wB, wO, b_off, b_def, ymain, statsRaw);
  k_final<<<512, 512, 0, stream>>>(xpad, wS, ymain, statsRaw, gamma, beta, b_sc, out);
}

// Round 9
// 155.880 us; speedup vs baseline: 1.4084x; 1.4084x over previous
//
#include <hip/hip_runtime.h>

typedef __attribute__((ext_vector_type(8))) short bf16x8;
typedef __attribute__((ext_vector_type(4))) float f32x4;

__device__ __forceinline__ float bf2f(unsigned short u) {
  return __uint_as_float(((unsigned int)u) << 16);
}
__device__ __forceinline__ unsigned short f2bf(float f) {
  unsigned int u = __float_as_uint(f);
  u += 0x7fffu + ((u >> 16) & 1u);
  return (unsigned short)(u >> 16);
}

// ---------------- workspace layout (bytes) ----------------
constexpr size_t OFF_XPAD = 0;
constexpr size_t SZ_XPAD  = (size_t)8 * 66 * 66 * 128 * 2;        // 8,921,088
constexpr size_t OFF_WB   = OFF_XPAD + SZ_XPAD;
constexpr size_t SZ_WB    = (size_t)9 * 16 * 256 * 8 * 2;         // 589,824
constexpr size_t OFF_WS2  = OFF_WB + SZ_WB;
constexpr size_t SZ_WS2   = (size_t)16 * 256 * 8 * 2;             // 65,536
constexpr size_t OFF_WO   = OFF_WS2 + SZ_WS2;
constexpr size_t SZ_WO    = (size_t)9 * 16 * 32 * 8 * 2;          // 73,728
// y_main bf16, FRAGMENT-LINEAR instruction-contiguous: [512 blocks][4 k][512 t][8]
constexpr size_t OFF_YM   = OFF_WO + SZ_WO;
constexpr size_t SZ_YM    = (size_t)512 * 512 * 32 * 2;           // 16,777,216
constexpr size_t OFF_SR   = OFF_YM + SZ_YM;                        // statsRaw [8][256][2] f32
constexpr size_t SZ_SR    = (size_t)8 * 256 * 2 * 4;              // 16,384

// XCD swizzle: xcd = blockIdx.x % 8. b = blk&7 -> batch b on XCD b; per-XCD L2
// working set = 1 batch xpad (1.1MB) + ymain slice (2MB) + weights (<0.7MB) < 4MB L2.
// Verified R2: FETCH 26.4->7.3MB. BN stats via per-batch atomics (verified R6).
// R8 lesson: NO nontemporal anywhere — NT bypasses L2 -> partial-line RMW (WRITE 85MB
// for 33.5MB out) AND kills the cross-kernel L2 reuse the swizzle exists for.
// ymain layout is instruction-contiguous (k-major) so each wave store = 1KB contig.

// ---------------- prep: x transpose (0..511) + weight pack (512..689) + stats zero (690) ----------------
__global__ __launch_bounds__(256) void k_prep(const float* __restrict__ x,
                                              unsigned short* __restrict__ xp,
                                              const float* __restrict__ wdef,
                                              const float* __restrict__ wsc,
                                              const float* __restrict__ woff,
                                              unsigned short* __restrict__ wB,
                                              unsigned short* __restrict__ wS,
                                              unsigned short* __restrict__ wO,
                                              float* __restrict__ statsRaw) {
  int t = threadIdx.x;
  if (blockIdx.x == 690) {            // zero BN accumulators (graph-replay safe)
    for (int i = t; i < 4096; i += 256) statsRaw[i] = 0.f;
    return;
  }
  if (blockIdx.x >= 512) {            // ---- weight packing: 8 contiguous elems/thread ----
    int base = ((blockIdx.x - 512) * 256 + t) * 8;
    unsigned short w8[8];
    if (base < 294912) {
      int n = (base >> 3) & 255, kb = (base >> 11) & 15, tap = base >> 15;
#pragma unroll
      for (int j = 0; j < 8; ++j)
        w8[j] = f2bf(wdef[((size_t)n * 128 + kb * 8 + j) * 9 + tap]);
      *(bf16x8*)(wB + base) = *(const bf16x8*)w8;
    } else if (base < 327680) {
      int i0 = base - 294912;
      int n = (i0 >> 3) & 255, kb = i0 >> 11;
#pragma unroll
      for (int j = 0; j < 8; ++j)
        w8[j] = f2bf(wsc[(size_t)n * 128 + kb * 8 + j]);
      *(bf16x8*)(wS + i0) = *(const bf16x8*)w8;
    } else {
      int i0 = base - 327680;
      int n = (i0 >> 3) & 31, kb = (i0 >> 8) & 15, tap = i0 >> 12;
#pragma unroll
      for (int j = 0; j < 8; ++j)
        w8[j] = f2bf(n < 18 ? woff[((size_t)n * 128 + kb * 8 + j) * 9 + tap] : 0.f);
      *(bf16x8*)(wO + i0) = *(const bf16x8*)w8;
    }
    return;
  }
  // ---- x: NCHW fp32 -> NHWC bf16 zero-padded (+ halo zeroing) ----
  int blk = blockIdx.x;               // 512; b = blk&7 (XCD-local), h = blk>>3
  int b = blk & 7, h = blk >> 3;
  __shared__ unsigned short xt[128 * 68];   // [c][w], stride 68
  {
    unsigned short* base = xp + (size_t)b * 66 * 66 * 128;
    ushort4 z4 = {0, 0, 0, 0};
    if (t < 64) {                     // side columns of padded row h+1
      int col = (t >> 5) ? 65 : 0;
      int i = t & 31;
      *(ushort4*)(base + ((size_t)(h + 1) * 66 + col) * 128 + i * 4) = z4;
    }
    if (h == 0) {                     // top and bottom padded rows
      for (int i = t; i < 2112; i += 256) {
        *(ushort4*)(base + (size_t)i * 4) = z4;
        *(ushort4*)(base + (size_t)65 * 66 * 128 + (size_t)i * 4) = z4;
      }
    }
  }
  {
    // lane-coalesced load: consecutive lanes -> consecutive float4
#pragma unroll
    for (int i4 = 0; i4 < 8; ++i4) {
      int idx = t + i4 * 256;         // 0..2047 over 128 rows x 16 float4
      int row = idx >> 4, col = (idx & 15) * 4;
      float4 f = *(const float4*)&x[(((size_t)b * 128 + row) * 64 + h) * 64 + col];
      ushort4 u4;
      u4.x = f2bf(f.x); u4.y = f2bf(f.y); u4.z = f2bf(f.z); u4.w = f2bf(f.w);
      *(ushort4*)&xt[row * 68 + col] = u4;
    }
  }
  __syncthreads();
  {
    // column gather: lane = w (2-way bank alias only), cg = channel group
    int w = t & 63, cg = t >> 6;
    unsigned short tmp[32];
#pragma unroll
    for (int i = 0; i < 32; ++i) tmp[i] = xt[(cg * 32 + i) * 68 + w];
    unsigned short* dst = xp + ((size_t)(b * 66 + h + 1) * 66 + (w + 1)) * 128 + cg * 32;
#pragma unroll
    for (int i8 = 0; i8 < 4; ++i8)
      *(bf16x8*)(dst + i8 * 8) = *(const bf16x8*)&tmp[i8 * 8];
  }
}

// ---------------- main: offset conv + deform-sample + 3x3 conv GEMM + BN atomics ----------------
// 512 blocks x 512 thr (8 waves); Breg preload keeps MFMA off the vmcnt FIFO chain.
// Epilogue: fragment-linear ymain dump (no LDS, no barriers), k-major so each
// wave-wide store instruction writes 1KB contiguous (full lines).
__global__ __launch_bounds__(512, 4) void k_main(const unsigned short* __restrict__ xp,
                                                 const unsigned short* __restrict__ wB,
                                                 const unsigned short* __restrict__ wO,
                                                 const float* __restrict__ boff,
                                                 const float* __restrict__ bdef,
                                                 unsigned short* __restrict__ ymain,
                                                 float* __restrict__ statsRaw) {
  int blk = blockIdx.x;               // 512; b = blk&7 (XCD-local), h = blk>>3
  int b = blk & 7, h = blk >> 3;
  int t = threadIdx.x;
  int lane = t & 63, wid = t >> 6;    // 8 waves
  int m = lane & 15, quad = lane >> 4;
  __shared__ __align__(16) unsigned short At[2][64 * 136];  // 2 x 17408 B
  __shared__ float offsL[9][64][2];                          // 4608 B

  // ---- phase 0: inline offset conv (waves 0-3 compute this row's 18 offsets -> LDS) ----
  if (wid < 4) {
    f32x4 a0 = {0.f, 0.f, 0.f, 0.f}, a1 = {0.f, 0.f, 0.f, 0.f};
    int px = wid * 16 + m;
    const unsigned short* xbase = xp + ((size_t)(b * 66 + h) * 66 + px) * 128 + quad * 8;
    for (int tap = 0; tap < 9; ++tap) {
      const unsigned short* arow = xbase + ((tap / 3) * 66 + (tap % 3)) * 128;
#pragma unroll
      for (int kk = 0; kk < 4; ++kk) {
        bf16x8 a = *(const bf16x8*)(arow + kk * 32);
        const unsigned short* bb = wO + (size_t)(tap * 16 + kk * 4 + quad) * 256;
        bf16x8 b0 = *(const bf16x8*)(bb + m * 8);
        bf16x8 b1 = *(const bf16x8*)(bb + (16 + m) * 8);
        a0 = __builtin_amdgcn_mfma_f32_16x16x32_bf16(a, b0, a0, 0, 0, 0);
        a1 = __builtin_amdgcn_mfma_f32_16x16x32_bf16(a, b1, a1, 0, 0, 0);
      }
    }
#pragma unroll
    for (int r = 0; r < 4; ++r) {
      int pxs = wid * 16 + quad * 4 + r;
      offsL[m >> 1][pxs][m & 1] = a0[r] + boff[m];   // n=m in [0,16): tap=n>>1, comp=n&1
      if (m < 2) offsL[8][pxs][m] = a1[r] + boff[16 + m];
    }
  }

  f32x4 acc[4][2];
#pragma unroll
  for (int i = 0; i < 4; ++i)
#pragma unroll
    for (int j = 0; j < 2; ++j) acc[i][j] = (f32x4){0.f, 0.f, 0.f, 0.f};

  // sampling role: thread = px_s*8 + sub; 8 consecutive lanes cover one 128B chunk
  int px_s = t >> 3, sub = t & 7;
  const unsigned short* xb_base = xp + (size_t)b * 66 * 66 * 128;
  int nb = wid * 32;                  // mfma role: 32-ch N slice per wave, M=64 shared

  bf16x8 Breg[4][2];                  // this tap's wB fragments, preloaded
  auto loadB = [&](int tap) {
#pragma unroll
    for (int kk = 0; kk < 4; ++kk)
#pragma unroll
      for (int ns = 0; ns < 2; ++ns)
        Breg[kk][ns] = *(const bf16x8*)(wB + ((size_t)(tap * 16 + kk * 4 + quad) * 256 + nb + ns * 16 + m) * 8);
  };

  auto sample_prep = [&](int tap, float* wgt, const unsigned short** p) {
    float2 ov = *(const float2*)&offsL[tap][px_s][0];
    int ky = tap / 3 - 1, kx = tap % 3 - 1;
    float py = (float)(h + ky) + ov.x;
    float pxf = (float)(px_s + kx) + ov.y;
    float y0f = floorf(py), x0f = floorf(pxf);
    float fy = py - y0f, fx = pxf - x0f;
    int iy0 = (int)y0f, ix0 = (int)x0f;
#pragma unroll
    for (int j = 0; j < 4; ++j) {
      int iy = iy0 + (j >> 1), ix = ix0 + (j & 1);
      float wy = (j >> 1) ? fy : 1.f - fy;
      float wx = (j & 1) ? fx : 1.f - fx;
      bool valid = (iy >= 0) && (iy < 64) && (ix >= 0) && (ix < 64);
      int iyc = min(max(iy, 0), 63), ixc = min(max(ix, 0), 63);
      wgt[j] = valid ? wy * wx : 0.f;
      p[j] = xb_base + ((size_t)(iyc + 1) * 66 + (ixc + 1)) * 128 + sub * 8;
    }
  };
  auto load_g1 = [&](const unsigned short** p, int g, bf16x8* v) {
#pragma unroll
    for (int j = 0; j < 4; ++j)
      v[j] = *(const bf16x8*)(p[j] + g * 64);
  };
  auto store_g1 = [&](unsigned short* dst, int g, const float* wgt, bf16x8* v) {
    bf16x8 o;
#pragma unroll
    for (int j = 0; j < 8; ++j) {
      float s = fmaf(wgt[0], bf2f((unsigned short)v[0][j]),
                fmaf(wgt[1], bf2f((unsigned short)v[1][j]),
                fmaf(wgt[2], bf2f((unsigned short)v[2][j]),
                     wgt[3] * bf2f((unsigned short)v[3][j]))));
      o[j] = (short)f2bf(s);
    }
    *(bf16x8*)(dst + g * 64) = o;
  };
  auto mfma_half = [&](const unsigned short* buf, int kk0) {
#pragma unroll
    for (int kk = kk0; kk < kk0 + 2; ++kk) {
      bf16x8 af[4];
#pragma unroll
      for (int ms = 0; ms < 4; ++ms)
        af[ms] = *(const bf16x8*)(buf + (ms * 16 + m) * 136 + kk * 32 + quad * 8);
#pragma unroll
      for (int ns = 0; ns < 2; ++ns)
#pragma unroll
        for (int ms = 0; ms < 4; ++ms)
          acc[ms][ns] = __builtin_amdgcn_mfma_f32_16x16x32_bf16(af[ms], Breg[kk][ns], acc[ms][ns], 0, 0, 0);
    }
  };

  // prologue: B-frags for tap 0, then sample tap 0 into buf 0
  loadB(0);
  __syncthreads();                    // offsL ready
  {
    float wgt[4]; const unsigned short* p[4]; bf16x8 v0[4], v1[4];
    sample_prep(0, wgt, p);
    unsigned short* dst = &At[0][px_s * 136 + sub * 8];
    load_g1(p, 0, v0); load_g1(p, 1, v1);
    store_g1(dst, 0, wgt, v0); store_g1(dst, 1, wgt, v1);
  }
#pragma unroll
  for (int tap = 0; tap < 9; ++tap) {
    __syncthreads();
    const unsigned short* cur = At[tap & 1];
    unsigned short* dst = &At[(tap + 1) & 1][px_s * 136 + sub * 8];
    if (tap < 8) {
      float wgt[4]; const unsigned short* p[4]; bf16x8 v0[4], v1[4];
      sample_prep(tap + 1, wgt, p);
      load_g1(p, 0, v0);
      load_g1(p, 1, v1);
      mfma_half(cur, 0);              // regs + ds_read only: no vmcnt dependence
      store_g1(dst, 0, wgt, v0);
      mfma_half(cur, 2);
      loadB(tap + 1);                 // prefetch next tap's B
      store_g1(dst, 1, wgt, v1);
    } else {
      mfma_half(cur, 0);
      mfma_half(cur, 2);
    }
  }

  // ---- epilogue: bias + BN atomics + fragment-linear ymain dump (no LDS) ----
#pragma unroll
  for (int ns = 0; ns < 2; ++ns) {
    int n = nb + ns * 16 + m;
    float bias = bdef[n];
    float s = 0.f, q = 0.f;
#pragma unroll
    for (int ms = 0; ms < 4; ++ms)
#pragma unroll
      for (int r = 0; r < 4; ++r) {
        float v = acc[ms][ns][r] + bias;
        acc[ms][ns][r] = v;
        s += v;
        q += v * v;
      }
    s += __shfl_xor(s, 16); s += __shfl_xor(s, 32);
    q += __shfl_xor(q, 16); q += __shfl_xor(q, 32);
    if (quad == 0) {                  // 64 blocks share each address (batch-local)
      atomicAdd(&statsRaw[((size_t)b * 256 + n) * 2 + 0], s);
      atomicAdd(&statsRaw[((size_t)b * 256 + n) * 2 + 1], q);
    }
  }
  {
    unsigned short yfrag[32];
#pragma unroll
    for (int ns = 0; ns < 2; ++ns)
#pragma unroll
      for (int ms = 0; ms < 4; ++ms)
#pragma unroll
        for (int r = 0; r < 4; ++r)
          yfrag[ns * 16 + ms * 4 + r] = f2bf(acc[ms][ns][r]);
    // k-major: each wave-wide store = 16B x 64 consecutive lanes = 1KB contiguous
    unsigned short* dst = ymain + (size_t)blk * 16384 + t * 8;
#pragma unroll
    for (int k = 0; k < 4; ++k)
      *(bf16x8*)(dst + k * 4096) = *(const bf16x8*)&yfrag[k * 8];
  }
}

// ---------------- final: stats finalize + 1x1 shortcut MFMA + BN apply + ReLU + NCHW store ----------------
// SAME 512x512 geometry as k_main: ymain read back as raw fragments (L2-hot, same XCD),
// combined in registers; LDS used once for the NCHW transpose-store (per 128-ch half).
__global__ __launch_bounds__(512, 4) void k_final(const unsigned short* __restrict__ xp,
                                                  const unsigned short* __restrict__ wS,
                                                  const unsigned short* __restrict__ ymain,
                                                  const float* __restrict__ statsRaw,
                                                  const float* __restrict__ gamma,
                                                  const float* __restrict__ beta,
                                                  const float* __restrict__ bsc,
                                                  float* __restrict__ out) {
  int blk = blockIdx.x;               // 512; b = blk&7 (XCD-local), h = blk>>3
  int b = blk & 7, h = blk >> 3;
  int t = threadIdx.x;
  int lane = t & 63, wid = t >> 6;
  int m = lane & 15, quad = lane >> 4;
  __shared__ __align__(16) float tr[128 * 68]; // 34,816 B (one 128-ch half x 64 px)
  __shared__ float sAB[512];                   // [0:256) scale, [256:512) shift
  // stats finalize (8 adds/channel from 16KB L2-resident buffer)
  if (t < 256) {
    float s = 0.f, q = 0.f;
#pragma unroll
    for (int i = 0; i < 8; ++i) {
      float2 pq = *(const float2*)&statsRaw[((size_t)i * 256 + t) * 2];
      s += pq.x;
      q += pq.y;
    }
    float mean = s * (1.f / 32768.f);
    float var = q * (1.f / 32768.f) - mean * mean;
    float inv = rsqrtf(var + 1e-5f);
    float A = gamma[t] * inv;
    sAB[t] = A;
    sAB[256 + t] = beta[t] - mean * A;
  }
  // 1x1 shortcut MFMA, k_main geometry: M=64 px, per-wave N=32
  f32x4 accS[4][2];
#pragma unroll
  for (int i = 0; i < 4; ++i)
#pragma unroll
    for (int j = 0; j < 2; ++j) accS[i][j] = (f32x4){0.f, 0.f, 0.f, 0.f};
  const unsigned short* xrow = xp + ((size_t)(b * 66 + h + 1) * 66 + 1) * 128;
  int nb = wid * 32;
#pragma unroll
  for (int kk = 0; kk < 4; ++kk) {
    bf16x8 af[4];
#pragma unroll
    for (int ms = 0; ms < 4; ++ms)
      af[ms] = *(const bf16x8*)(xrow + (ms * 16 + m) * 128 + kk * 32 + quad * 8);
#pragma unroll
    for (int ns = 0; ns < 2; ++ns) {
      bf16x8 bfr = *(const bf16x8*)(wS + ((size_t)(kk * 4 + quad) * 256 + nb + ns * 16 + m) * 8);
#pragma unroll
      for (int ms = 0; ms < 4; ++ms)
        accS[ms][ns] = __builtin_amdgcn_mfma_f32_16x16x32_bf16(af[ms], bfr, accS[ms][ns], 0, 0, 0);
    }
  }
  // y fragments back, same k-major mapping (wave-contiguous 1KB reads, L2-hot)
  bf16x8 yf[4];
  {
    const unsigned short* ysrc = ymain + (size_t)blk * 16384 + t * 8;
#pragma unroll
    for (int k = 0; k < 4; ++k)
      yf[k] = *(const bf16x8*)(ysrc + k * 4096);
  }
  __syncthreads();                    // sAB ready
  int pass_own = wid >> 2;            // waves 0-3 own n<128, waves 4-7 own n>=128
  for (int pass = 0; pass < 2; ++pass) {
    if (pass_own == pass) {
#pragma unroll
      for (int ns = 0; ns < 2; ++ns) {
        int n = nb + ns * 16 + m;
        float A = sAB[n], Bc = sAB[256 + n], bs = bsc[n];
        int nl = n - pass * 128;
#pragma unroll
        for (int ms = 0; ms < 4; ++ms)
#pragma unroll
          for (int r = 0; r < 4; ++r) {
            int e = ns * 16 + ms * 4 + r;
            float y = bf2f((unsigned short)yf[e >> 3][e & 7]);
            float v = fmaf(y, A, Bc) + accS[ms][ns][r] + bs;
            tr[nl * 68 + ms * 16 + quad * 4 + r] = fmaxf(v, 0.f);
          }
      }
    }
    __syncthreads();
    {
      int nl = t >> 2, q4 = t & 3;    // 128 ch-rows x 4 px-quarters
      float* orow = out + ((size_t)(b * 256 + pass * 128 + nl) * 64 + h) * 64 + q4 * 16;
      const float* lrow = &tr[nl * 68 + q4 * 16];
#pragma unroll
      for (int i4 = 0; i4 < 4; ++i4)
        *(f32x4*)(orow + i4 * 4) = *(const f32x4*)(lrow + i4 * 4);
    }
    __syncthreads();
  }
}

extern "C" void kernel_launch(void* const* d_in, const int* in_sizes, int n_in,
                              void* d_out, int out_size, void* d_ws, size_t ws_size,
                              hipStream_t stream) {
  const float* x     = (const float*)d_in[0];
  const float* w_off = (const float*)d_in[1];
  const float* b_off = (const float*)d_in[2];
  const float* w_def = (const float*)d_in[3];
  const float* b_def = (const float*)d_in[4];
  const float* gamma = (const float*)d_in[5];
  const float* beta  = (const float*)d_in[6];
  const float* w_sc  = (const float*)d_in[7];
  const float* b_sc  = (const float*)d_in[8];
  float* out = (float*)d_out;

  char* ws = (char*)d_ws;
  unsigned short* xpad  = (unsigned short*)(ws + OFF_XPAD);
  unsigned short* wB    = (unsigned short*)(ws + OFF_WB);
  unsigned short* wS    = (unsigned short*)(ws + OFF_WS2);
  unsigned short* wO    = (unsigned short*)(ws + OFF_WO);
  unsigned short* ymain = (unsigned short*)(ws + OFF_YM);
  float* statsRaw       = (float*)(ws + OFF_SR);

  k_prep<<<691, 256, 0, stream>>>(x, xpad, w_def, w_sc, w_off, wB, wS, wO, statsRaw);
  k_main<<<512, 512, 0, stream>>>(xpad, wB, wO, b_off, b_def, ymain, statsRaw);
  k_final<<<512, 512, 0, stream>>>(xpad, wS, ymain, statsRaw, gamma, beta, b_sc, out);
}